// Round 3
// baseline (205.076 us; speedup 1.0000x reference)
//
#include <hip/hip_runtime.h>
#include <hip/hip_bf16.h>
#include <stdint.h>

#define NE    8
#define NTOK  1024
#define NH    1024
#define NI    1024
#define N13   2048
#define NPAIR 2048
#define SROW  40    // LDS row stride in u16 (80 B): 16B-aligned, banks sweep period-8 -> conflict-free

typedef __attribute__((ext_vector_type(8))) short short8;
typedef __attribute__((ext_vector_type(4))) float f32x4;
typedef unsigned short u16;
typedef unsigned int   u32;

// fp32 -> bf16 round-to-nearest-even
__device__ __forceinline__ u16 f2bf(float x) {
    union { float f; u32 u; } v; v.f = x;
    return (u16)((v.u + 0x7fffu + ((v.u >> 16) & 1u)) >> 16);
}

__device__ __forceinline__ uint4 pack8(const float* f) {
    uint4 o;
    o.x = f2bf(f[0]) | ((u32)f2bf(f[1]) << 16);
    o.y = f2bf(f[2]) | ((u32)f2bf(f[3]) << 16);
    o.z = f2bf(f[4]) | ((u32)f2bf(f[5]) << 16);
    o.w = f2bf(f[6]) | ((u32)f2bf(f[7]) << 16);
    return o;
}

// ---------------------------------------------------------------------------
// Routing: renormalized top-2 softmax == 2-way softmax over top-2 logits.
// ---------------------------------------------------------------------------
__global__ __launch_bounds__(256) void route_kernel(
    const float* __restrict__ logits,
    int* __restrict__ counts, int* __restrict__ pair_tok,
    float* __restrict__ pair_w)
{
    __shared__ int s_cnt[NE];
    __shared__ int s_base[NE];
    const int tid = threadIdx.x;
    if (tid < NE) s_cnt[tid] = 0;
    __syncthreads();

    int eA[4][2]; int slotA[4][2]; float wA[4][2];

    #pragma unroll
    for (int i = 0; i < 4; i++) {
        const int t = tid * 4 + i;
        float l[NE];
        #pragma unroll
        for (int e = 0; e < NE; e++) l[e] = logits[t * NE + e];
        int i0 = 0;
        #pragma unroll
        for (int e = 1; e < NE; e++) if (l[e] > l[i0]) i0 = e;
        int i1 = -1;
        #pragma unroll
        for (int e = 0; e < NE; e++) {
            if (e == i0) continue;
            if (i1 < 0 || l[e] > l[i1]) i1 = e;
        }
        const float e10 = __expf(l[i1] - l[i0]);
        const float inv = 1.0f / (1.0f + e10);
        eA[i][0] = i0; eA[i][1] = i1;
        wA[i][0] = inv; wA[i][1] = e10 * inv;
        slotA[i][0] = atomicAdd(&s_cnt[i0], 1);
        slotA[i][1] = atomicAdd(&s_cnt[i1], 1);
    }
    __syncthreads();
    if (tid == 0) {
        int acc = 0;
        #pragma unroll
        for (int e = 0; e < NE; e++) { s_base[e] = acc; acc += s_cnt[e]; }
    }
    __syncthreads();
    if (tid < NE) counts[tid] = s_cnt[tid];
    #pragma unroll
    for (int i = 0; i < 4; i++) {
        const int t = tid * 4 + i;
        #pragma unroll
        for (int k = 0; k < 2; k++) {
            const int p = s_base[eA[i][k]] + slotA[i][k];
            pair_tok[p] = t;
            pair_w[p]   = wA[i][k];
        }
    }
}

// ---------------------------------------------------------------------------
__device__ __forceinline__ bool find_tile(
    const int* __restrict__ counts, int tile, int bm, int ntn,
    int& e_o, int& mt_o, int& nt_o, int& cnt_o, int& base_o)
{
    int base = 0;
    #pragma unroll
    for (int e = 0; e < NE; e++) {
        const int cnt = counts[e];
        const int mtiles = (cnt + bm - 1) / bm;
        const int tiles = mtiles * ntn;
        if (tile < tiles) {
            e_o = e; mt_o = tile / ntn; nt_o = tile - (tile / ntn) * ntn;
            cnt_o = cnt; base_o = base; return true;
        }
        tile -= tiles; base += cnt;
    }
    return false;
}

// ---------------------------------------------------------------------------
// X: fp32 -> bf16 copy
// ---------------------------------------------------------------------------
__global__ __launch_bounds__(256) void cvt_x_kernel(
    const float* __restrict__ src, u16* __restrict__ dst)
{
    const int i = blockIdx.x * 256 + threadIdx.x;
    const float4* s = (const float4*)src;
    const float4 a = s[2 * i], b = s[2 * i + 1];
    float f[8] = {a.x, a.y, a.z, a.w, b.x, b.y, b.z, b.w};
    *(uint4*)(dst + (size_t)i * 8) = pack8(f);
}

// ---------------------------------------------------------------------------
// GEMM1 (bf16 MFMA): act[p][c] = silu(x.Wg[c]) * (x.Wu[c])
// BM=128 pairs, 64 act cols (128 weight cols), BK=32. Waves 2x2.
// B converted+transposed in-register from original fp32 W13 layout.
// ---------------------------------------------------------------------------
__global__ __launch_bounds__(256) void gemm1_kernel(
    const u16* __restrict__ Xb, const float* __restrict__ W13,
    const int* __restrict__ counts, const int* __restrict__ pair_tok,
    u16* __restrict__ act)
{
    int e, mt, nt, cnt, base;
    if (!find_tile(counts, blockIdx.x, 128, NI / 64, e, mt, nt, cnt, base)) return;

    __shared__ u16 As[128 * SROW];
    __shared__ u16 Bs[128 * SROW];   // rows 0..63 gate, 64..127 up; [n][k] padded

    const int tid = threadIdx.x;
    const int ct  = nt * 64;

    // A staging: 2 x uint4 (8 bf16) per thread
    const int ar = tid >> 2, aq = tid & 3;
    const int t0 = pair_tok[base + min(mt * 128 + ar, cnt - 1)];
    const int t1 = pair_tok[base + min(mt * 128 + 64 + ar, cnt - 1)];
    const u16* ga0 = Xb + (size_t)t0 * NH + aq * 8;
    const u16* ga1 = Xb + (size_t)t1 * NH + aq * 8;
    u16* la0 = As + ar * SROW + aq * 8;
    u16* la1 = As + (64 + ar) * SROW + aq * 8;

    // B staging: 16 k-strided fp32 loads (lane-coalesced), pack -> 2 x 16B rows
    const int bn = tid & 127;            // B LDS row
    const int kh = tid >> 7;             // k half (16 k's each)
    const int gcol = (bn < 64) ? (ct + bn) : (NI + ct + bn - 64);
    const float* gb = W13 + (size_t)e * NH * N13 + (size_t)kh * 16 * N13 + gcol;
    u16* lb = Bs + bn * SROW + kh * 16;

    const int lane = tid & 63, w = tid >> 6;
    const int quad = lane >> 4, lid = lane & 15;
    const int rw = w >> 1, cw = w & 1;

    const u16* afp[4]; const u16* bgp[2]; const u16* bup[2];
    #pragma unroll
    for (int mi = 0; mi < 4; mi++)
        afp[mi] = As + (rw * 64 + mi * 16 + lid) * SROW + quad * 8;
    #pragma unroll
    for (int nj = 0; nj < 2; nj++) {
        bgp[nj] = Bs + (cw * 32 + nj * 16 + lid) * SROW + quad * 8;
        bup[nj] = Bs + (64 + cw * 32 + nj * 16 + lid) * SROW + quad * 8;
    }

    f32x4 accg[4][2] = {};
    f32x4 accu[4][2] = {};

    // prologue prefetch (k0 = 0)
    uint4 a0 = *(const uint4*)ga0;
    uint4 a1 = *(const uint4*)ga1;
    float bf[16];
    #pragma unroll
    for (int j = 0; j < 16; j++) bf[j] = gb[(size_t)j * N13];

    for (int k0 = 0; k0 < NH; k0 += 32) {
        *(uint4*)la0 = a0;
        *(uint4*)la1 = a1;
        *(uint4*)lb       = pack8(bf);
        *(uint4*)(lb + 8) = pack8(bf + 8);
        __syncthreads();

        if (k0 + 32 < NH) {       // prefetch next chunk; latency hides under MFMA
            a0 = *(const uint4*)(ga0 + k0 + 32);
            a1 = *(const uint4*)(ga1 + k0 + 32);
            #pragma unroll
            for (int j = 0; j < 16; j++) bf[j] = gb[(size_t)(k0 + 32 + j) * N13];
        }

        short8 a[4], bg[2], bu[2];
        #pragma unroll
        for (int mi = 0; mi < 4; mi++) a[mi] = *(const short8*)afp[mi];
        #pragma unroll
        for (int nj = 0; nj < 2; nj++) {
            bg[nj] = *(const short8*)bgp[nj];
            bu[nj] = *(const short8*)bup[nj];
        }
        #pragma unroll
        for (int mi = 0; mi < 4; mi++) {
            #pragma unroll
            for (int nj = 0; nj < 2; nj++) {
                accg[mi][nj] = __builtin_amdgcn_mfma_f32_16x16x32_bf16(a[mi], bg[nj], accg[mi][nj], 0, 0, 0);
                accu[mi][nj] = __builtin_amdgcn_mfma_f32_16x16x32_bf16(a[mi], bu[nj], accu[mi][nj], 0, 0, 0);
            }
        }
        __syncthreads();
    }

    #pragma unroll
    for (int mi = 0; mi < 4; mi++) {
        #pragma unroll
        for (int nj = 0; nj < 2; nj++) {
            const int col = ct + cw * 32 + nj * 16 + lid;
            #pragma unroll
            for (int r = 0; r < 4; r++) {
                const int row = mt * 128 + rw * 64 + mi * 16 + quad * 4 + r;
                if (row < cnt) {
                    const float g = accg[mi][nj][r], u = accu[mi][nj][r];
                    const float s = g / (1.0f + __expf(-g)) * u;
                    act[(size_t)(base + row) * NI + col] = f2bf(s);
                }
            }
        }
    }
}

// ---------------------------------------------------------------------------
// GEMM2 (bf16 MFMA): out[tok] += w_p * (act[p] . W2[e][:,h])
// BM=64 pairs, BN=128 h cols, BK=32. Waves 1x4. Atomic scatter-combine.
// ---------------------------------------------------------------------------
__global__ __launch_bounds__(256) void gemm2_kernel(
    const u16* __restrict__ act, const float* __restrict__ W2,
    const int* __restrict__ counts, const int* __restrict__ pair_tok,
    const float* __restrict__ pair_w, float* __restrict__ out)
{
    int e, mt, nt, cnt, base;
    if (!find_tile(counts, blockIdx.x, 64, NH / 128, e, mt, nt, cnt, base)) return;

    __shared__ u16 As[64 * SROW];
    __shared__ u16 Bs[128 * SROW];

    const int tid = threadIdx.x;
    const int ct  = nt * 128;

    const int ar = tid >> 2, aq = tid & 3;
    const int prow = base + min(mt * 64 + ar, cnt - 1);
    const u16* ga = act + (size_t)prow * NI + aq * 8;
    u16* la = As + ar * SROW + aq * 8;

    const int bn = tid & 127;
    const int kh = tid >> 7;
    const float* gb = W2 + (size_t)e * NI * NH + (size_t)kh * 16 * NH + ct + bn;
    u16* lb = Bs + bn * SROW + kh * 16;

    const int lane = tid & 63, w = tid >> 6;
    const int quad = lane >> 4, lid = lane & 15;

    const u16* afp[4]; const u16* bfp[2];
    #pragma unroll
    for (int mi = 0; mi < 4; mi++)
        afp[mi] = As + (mi * 16 + lid) * SROW + quad * 8;
    #pragma unroll
    for (int nj = 0; nj < 2; nj++)
        bfp[nj] = Bs + (w * 32 + nj * 16 + lid) * SROW + quad * 8;

    f32x4 acc[4][2] = {};

    uint4 a0 = *(const uint4*)ga;
    float bf[16];
    #pragma unroll
    for (int j = 0; j < 16; j++) bf[j] = gb[(size_t)j * NH];

    for (int k0 = 0; k0 < NI; k0 += 32) {
        *(uint4*)la       = a0;
        *(uint4*)lb       = pack8(bf);
        *(uint4*)(lb + 8) = pack8(bf + 8);
        __syncthreads();

        if (k0 + 32 < NI) {
            a0 = *(const uint4*)(ga + k0 + 32);
            #pragma unroll
            for (int j = 0; j < 16; j++) bf[j] = gb[(size_t)(k0 + 32 + j) * NH];
        }

        short8 a[4], b[2];
        #pragma unroll
        for (int mi = 0; mi < 4; mi++) a[mi] = *(const short8*)afp[mi];
        #pragma unroll
        for (int nj = 0; nj < 2; nj++) b[nj] = *(const short8*)bfp[nj];
        #pragma unroll
        for (int mi = 0; mi < 4; mi++) {
            #pragma unroll
            for (int nj = 0; nj < 2; nj++)
                acc[mi][nj] = __builtin_amdgcn_mfma_f32_16x16x32_bf16(a[mi], b[nj], acc[mi][nj], 0, 0, 0);
        }
        __syncthreads();
    }

    #pragma unroll
    for (int mi = 0; mi < 4; mi++) {
        #pragma unroll
        for (int r = 0; r < 4; r++) {
            const int row = mt * 64 + mi * 16 + quad * 4 + r;
            if (row < cnt) {
                const int p = base + row;
                const int t = pair_tok[p];
                const float wgt = pair_w[p];
                #pragma unroll
                for (int nj = 0; nj < 2; nj++) {
                    const int col = ct + w * 32 + nj * 16 + lid;
                    atomicAdd(out + (size_t)t * NH + col, wgt * acc[mi][nj][r]);
                }
            }
        }
    }
}

// ---------------------------------------------------------------------------
extern "C" void kernel_launch(void* const* d_in, const int* in_sizes, int n_in,
                              void* d_out, int out_size, void* d_ws, size_t ws_size,
                              hipStream_t stream)
{
    const float* X      = (const float*)d_in[0];
    const float* logits = (const float*)d_in[1];
    const float* W13    = (const float*)d_in[2];
    const float* W2     = (const float*)d_in[3];
    float* out = (float*)d_out;

    char* ws = (char*)d_ws;
    int*   counts   = (int*)(ws + 0);
    int*   pair_tok = (int*)(ws + 256);              // 8 KiB
    float* pair_w   = (float*)(ws + 256 + 8192);     // 8 KiB
    u16*   Xb       = (u16*)(ws + 65536);            // 2 MiB
    u16*   act      = (u16*)(ws + 65536 + 2097152);  // 4 MiB

    hipMemsetAsync(d_out, 0, (size_t)NTOK * NH * sizeof(float), stream);
    route_kernel<<<1, 256, 0, stream>>>(logits, counts, pair_tok, pair_w);
    cvt_x_kernel<<<512, 256, 0, stream>>>(X, Xb);

    const int grid1 = (NPAIR / 128 + NE - 1) * (NI / 64);    // 368 max
    const int grid2 = (NPAIR / 64 + NE - 1) * (NH / 128);    // 312 max
    gemm1_kernel<<<grid1, 256, 0, stream>>>(Xb, W13, counts, pair_tok, act);
    gemm2_kernel<<<grid2, 256, 0, stream>>>(act, W2, counts, pair_tok, pair_w, out);
}

// Round 4
// 200.181 us; speedup vs baseline: 1.0245x; 1.0245x over previous
//
#include <hip/hip_runtime.h>
#include <hip/hip_bf16.h>
#include <stdint.h>

#define NE    8
#define NTOK  1024
#define NH    1024
#define NI    1024
#define N13   2048
#define NPAIR 2048

typedef __attribute__((ext_vector_type(8))) short short8;
typedef __attribute__((ext_vector_type(4))) float f32x4;
typedef unsigned short u16;
typedef unsigned int   u32;

// waitcnt immediates (gfx9 encoding): vmcnt[3:0] | expcnt<<4 | lgkmcnt<<8
#define WAIT_VM4 0x0F74   // vmcnt(4), exp/lgkm ignored
#define WAIT_VM3 0x0F73   // vmcnt(3)
#define WAIT_VM0 0x0F70   // vmcnt(0)

__device__ __forceinline__ u16 f2bf(float x) {
    union { float f; u32 u; } v; v.f = x;
    return (u16)((v.u + 0x7fffu + ((v.u >> 16) & 1u)) >> 16);
}

__device__ __forceinline__ void async_ld16(u16* lds, const u16* g) {
    __builtin_amdgcn_global_load_lds(
        (const __attribute__((address_space(1))) u32*)g,
        (__attribute__((address_space(3))) u32*)lds, 16, 0, 0);
}

// ---------------------------------------------------------------------------
// Routing
// ---------------------------------------------------------------------------
__global__ __launch_bounds__(256) void route_kernel(
    const float* __restrict__ logits,
    int* __restrict__ counts, int* __restrict__ pair_tok,
    float* __restrict__ pair_w)
{
    __shared__ int s_cnt[NE];
    __shared__ int s_base[NE];
    const int tid = threadIdx.x;
    if (tid < NE) s_cnt[tid] = 0;
    __syncthreads();

    int eA[4][2]; int slotA[4][2]; float wA[4][2];

    #pragma unroll
    for (int i = 0; i < 4; i++) {
        const int t = tid * 4 + i;
        float l[NE];
        #pragma unroll
        for (int e = 0; e < NE; e++) l[e] = logits[t * NE + e];
        int i0 = 0;
        #pragma unroll
        for (int e = 1; e < NE; e++) if (l[e] > l[i0]) i0 = e;
        int i1 = -1;
        #pragma unroll
        for (int e = 0; e < NE; e++) {
            if (e == i0) continue;
            if (i1 < 0 || l[e] > l[i1]) i1 = e;
        }
        const float e10 = __expf(l[i1] - l[i0]);
        const float inv = 1.0f / (1.0f + e10);
        eA[i][0] = i0; eA[i][1] = i1;
        wA[i][0] = inv; wA[i][1] = e10 * inv;
        slotA[i][0] = atomicAdd(&s_cnt[i0], 1);
        slotA[i][1] = atomicAdd(&s_cnt[i1], 1);
    }
    __syncthreads();
    if (tid == 0) {
        int acc = 0;
        #pragma unroll
        for (int e = 0; e < NE; e++) { s_base[e] = acc; acc += s_cnt[e]; }
    }
    __syncthreads();
    if (tid < NE) counts[tid] = s_cnt[tid];
    #pragma unroll
    for (int i = 0; i < 4; i++) {
        const int t = tid * 4 + i;
        #pragma unroll
        for (int k = 0; k < 2; k++) {
            const int p = s_base[eA[i][k]] + slotA[i][k];
            pair_tok[p] = t;
            pair_w[p]   = wA[i][k];
        }
    }
}

// ---------------------------------------------------------------------------
__device__ __forceinline__ bool find_tile(
    const int* __restrict__ counts, int tile, int bm, int ntn,
    int& e_o, int& mt_o, int& nt_o, int& cnt_o, int& base_o)
{
    int base = 0;
    #pragma unroll
    for (int e = 0; e < NE; e++) {
        const int cnt = counts[e];
        const int mtiles = (cnt + bm - 1) / bm;
        const int tiles = mtiles * ntn;
        if (tile < tiles) {
            e_o = e; mt_o = tile / ntn; nt_o = tile - (tile / ntn) * ntn;
            cnt_o = cnt; base_o = base; return true;
        }
        tile -= tiles; base += cnt;
    }
    return false;
}

// ---------------------------------------------------------------------------
// X: fp32 -> bf16 copy
// ---------------------------------------------------------------------------
__global__ __launch_bounds__(256) void cvt_x_kernel(
    const float* __restrict__ src, u16* __restrict__ dst)
{
    const int i = blockIdx.x * 256 + threadIdx.x;
    const float4* s = (const float4*)src;
    const float4 a = s[2 * i], b = s[2 * i + 1];
    uint4 o;
    o.x = f2bf(a.x) | ((u32)f2bf(a.y) << 16);
    o.y = f2bf(a.z) | ((u32)f2bf(a.w) << 16);
    o.z = f2bf(b.x) | ((u32)f2bf(b.y) << 16);
    o.w = f2bf(b.z) | ((u32)f2bf(b.w) << 16);
    *(uint4*)(dst + (size_t)i * 8) = o;
}

// ---------------------------------------------------------------------------
// Batched transpose+convert: src [E][K][N] fp32 -> dst [E][N][K] bf16.
// (verified in R2)
// ---------------------------------------------------------------------------
__global__ __launch_bounds__(256) void cvt_tr_kernel(
    const float* __restrict__ src, u16* __restrict__ dst, int K, int N)
{
    __shared__ float Ts[64][65];
    const int ktiles = K >> 6, ntiles = N >> 6;
    const int tpe = ktiles * ntiles;
    const int e = blockIdx.x / tpe;
    const int rem = blockIdx.x - e * tpe;
    const int kt = rem / ntiles, nt = rem - (rem / ntiles) * ntiles;
    const float* sb = src + ((size_t)e * K + (size_t)kt * 64) * N + nt * 64;
    const int tid = threadIdx.x;

    #pragma unroll
    for (int i = 0; i < 4; i++) {
        const int idx = tid + i * 256;
        const int r = idx >> 4, c = (idx & 15) << 2;
        const float4 v = *(const float4*)(sb + (size_t)r * N + c);
        Ts[r][c + 0] = v.x; Ts[r][c + 1] = v.y;
        Ts[r][c + 2] = v.z; Ts[r][c + 3] = v.w;
    }
    __syncthreads();
    u16* db = dst + ((size_t)e * N + (size_t)nt * 64) * K + kt * 64;
    #pragma unroll
    for (int i = 0; i < 2; i++) {
        const int u = tid + i * 256;
        const int n = u >> 3, k8 = (u & 7) << 3;
        uint4 o;
        o.x = f2bf(Ts[k8 + 0][n]) | ((u32)f2bf(Ts[k8 + 1][n]) << 16);
        o.y = f2bf(Ts[k8 + 2][n]) | ((u32)f2bf(Ts[k8 + 3][n]) << 16);
        o.z = f2bf(Ts[k8 + 4][n]) | ((u32)f2bf(Ts[k8 + 5][n]) << 16);
        o.w = f2bf(Ts[k8 + 6][n]) | ((u32)f2bf(Ts[k8 + 7][n]) << 16);
        *(uint4*)(db + (size_t)n * K + k8) = o;
    }
}

// ---------------------------------------------------------------------------
// GEMM1: act = silu(X.Wg)*(X.Wu). BM=128 pairs, 64 act cols (128 wcols),
// BK=32, waves 2x2. XOR-swizzled LDS (conflict-free b128 frag reads),
// double-buffered global_load_lds with raw vmcnt/s_barrier pipeline.
// ---------------------------------------------------------------------------
__global__ __launch_bounds__(256) void gemm1_kernel(
    const u16* __restrict__ Xb, const u16* __restrict__ W13t,
    const int* __restrict__ counts, const int* __restrict__ pair_tok,
    u16* __restrict__ act)
{
    int e, mt, nt, cnt, base;
    if (!find_tile(counts, blockIdx.x, 128, NI / 64, e, mt, nt, cnt, base)) return;

    __shared__ u16 As[2][128 * 32];   // [m][k] blocks, seg-swizzled
    __shared__ u16 Bs[2][128 * 32];   // rows 0..63 gate, 64..127 up

    const int tid = threadIdx.x;
    const int ct  = nt * 64;

    // --- staging sources (2 A blocks + 2 B blocks per thread) ---
    const int m0 = tid >> 2;                               // 0..63
    const int sw16 = (((tid & 3) ^ (m0 & 3)) << 3);        // swizzled k-seg (u16)
    const int t0 = pair_tok[base + min(mt * 128 + m0, cnt - 1)];
    const int t1 = pair_tok[base + min(mt * 128 + 64 + m0, cnt - 1)];
    const u16* ga0 = Xb + (size_t)t0 * NH + sw16;
    const u16* ga1 = Xb + (size_t)t1 * NH + sw16;
    const u16* gb0 = W13t + ((size_t)e * N13 + ct + m0) * 1024 + sw16;         // gate
    const u16* gb1 = W13t + ((size_t)e * N13 + NI + ct + m0) * 1024 + sw16;    // up

    // --- fragment read offsets (u16 units) ---
    const int lane = tid & 63, w = tid >> 6;
    const int quad = lane >> 4, lid = lane & 15;
    const int rw = w >> 1, cw = w & 1;
    const int fsw = (quad ^ (lid & 3)) << 3;
    int aoff[4], bgoff[2], buoff[2];
    #pragma unroll
    for (int mi = 0; mi < 4; mi++)
        aoff[mi] = (rw * 64 + mi * 16 + lid) * 32 + fsw;
    #pragma unroll
    for (int nj = 0; nj < 2; nj++) {
        bgoff[nj] = (cw * 32 + nj * 16 + lid) * 32 + fsw;
        buoff[nj] = (64 + cw * 32 + nj * 16 + lid) * 32 + fsw;
    }

    f32x4 accg[4][2] = {};
    f32x4 accu[4][2] = {};

#define ISSUE1(b, k0)                                        \
    {                                                        \
        async_ld16(&As[b][tid * 8],         ga0 + (k0));     \
        async_ld16(&As[b][(tid + 256) * 8], ga1 + (k0));     \
        async_ld16(&Bs[b][tid * 8],         gb0 + (k0));     \
        async_ld16(&Bs[b][(tid + 256) * 8], gb1 + (k0));     \
    }
#define COMP1(b)                                                               \
    {                                                                          \
        short8 av[4], gv[2], uv[2];                                            \
        _Pragma("unroll") for (int mi = 0; mi < 4; mi++)                       \
            av[mi] = *(const short8*)&As[b][aoff[mi]];                         \
        _Pragma("unroll") for (int nj = 0; nj < 2; nj++) {                     \
            gv[nj] = *(const short8*)&Bs[b][bgoff[nj]];                        \
            uv[nj] = *(const short8*)&Bs[b][buoff[nj]];                        \
        }                                                                      \
        _Pragma("unroll") for (int mi = 0; mi < 4; mi++)                       \
            _Pragma("unroll") for (int nj = 0; nj < 2; nj++) {                 \
                accg[mi][nj] = __builtin_amdgcn_mfma_f32_16x16x32_bf16(        \
                    av[mi], gv[nj], accg[mi][nj], 0, 0, 0);                    \
                accu[mi][nj] = __builtin_amdgcn_mfma_f32_16x16x32_bf16(        \
                    av[mi], uv[nj], accu[mi][nj], 0, 0, 0);                    \
            }                                                                  \
    }

    ISSUE1(0, 0);
    int buf = 0;
    for (int k0 = 32; k0 < NH; k0 += 32) {
        ISSUE1(buf ^ 1, k0);
        __builtin_amdgcn_s_waitcnt(WAIT_VM4);   // current buffer's 4 loads done
        __builtin_amdgcn_s_barrier();
        COMP1(buf);
        __builtin_amdgcn_s_barrier();           // all reads of buf done before reuse
        buf ^= 1;
    }
    __builtin_amdgcn_s_waitcnt(WAIT_VM0);
    __builtin_amdgcn_s_barrier();
    COMP1(buf);

    #pragma unroll
    for (int mi = 0; mi < 4; mi++) {
        #pragma unroll
        for (int nj = 0; nj < 2; nj++) {
            const int col = ct + cw * 32 + nj * 16 + lid;
            #pragma unroll
            for (int r = 0; r < 4; r++) {
                const int row = mt * 128 + rw * 64 + mi * 16 + quad * 4 + r;
                if (row < cnt) {
                    const float g = accg[mi][nj][r], u = accu[mi][nj][r];
                    const float s = g / (1.0f + __expf(-g)) * u;
                    act[(size_t)(base + row) * NI + col] = f2bf(s);
                }
            }
        }
    }
#undef ISSUE1
#undef COMP1
}

// ---------------------------------------------------------------------------
// GEMM2: out[tok] += w_p * (act[p] . W2t[e][h]). BM=128, BN=64, BK=32,
// waves 2x2. Same swizzle + dbuf pipeline. Atomic scatter-combine.
// ---------------------------------------------------------------------------
__global__ __launch_bounds__(256) void gemm2_kernel(
    const u16* __restrict__ act, const u16* __restrict__ W2t,
    const int* __restrict__ counts, const int* __restrict__ pair_tok,
    const float* __restrict__ pair_w, float* __restrict__ out)
{
    int e, mt, nt, cnt, base;
    if (!find_tile(counts, blockIdx.x, 128, NH / 64, e, mt, nt, cnt, base)) return;

    __shared__ u16 As[2][128 * 32];
    __shared__ u16 Bs[2][64 * 32];

    const int tid = threadIdx.x;
    const int ct  = nt * 64;

    const int m0 = tid >> 2;
    const int sw16 = (((tid & 3) ^ (m0 & 3)) << 3);
    const int p0 = base + min(mt * 128 + m0, cnt - 1);
    const int p1 = base + min(mt * 128 + 64 + m0, cnt - 1);
    const u16* ga0 = act + (size_t)p0 * NI + sw16;
    const u16* ga1 = act + (size_t)p1 * NI + sw16;
    const u16* gb0 = W2t + ((size_t)e * 1024 + ct + m0) * 1024 + sw16;

    const int lane = tid & 63, w = tid >> 6;
    const int quad = lane >> 4, lid = lane & 15;
    const int rw = w >> 1, cw = w & 1;
    const int fsw = (quad ^ (lid & 3)) << 3;
    int aoff[4], boff[2];
    #pragma unroll
    for (int mi = 0; mi < 4; mi++)
        aoff[mi] = (rw * 64 + mi * 16 + lid) * 32 + fsw;
    #pragma unroll
    for (int nj = 0; nj < 2; nj++)
        boff[nj] = (cw * 32 + nj * 16 + lid) * 32 + fsw;

    f32x4 acc[4][2] = {};

#define ISSUE2(b, k0)                                        \
    {                                                        \
        async_ld16(&As[b][tid * 8],         ga0 + (k0));     \
        async_ld16(&As[b][(tid + 256) * 8], ga1 + (k0));     \
        async_ld16(&Bs[b][tid * 8],         gb0 + (k0));     \
    }
#define COMP2(b)                                                               \
    {                                                                          \
        short8 av[4], bv[2];                                                   \
        _Pragma("unroll") for (int mi = 0; mi < 4; mi++)                       \
            av[mi] = *(const short8*)&As[b][aoff[mi]];                         \
        _Pragma("unroll") for (int nj = 0; nj < 2; nj++)                       \
            bv[nj] = *(const short8*)&Bs[b][boff[nj]];                         \
        _Pragma("unroll") for (int mi = 0; mi < 4; mi++)                       \
            _Pragma("unroll") for (int nj = 0; nj < 2; nj++)                   \
                acc[mi][nj] = __builtin_amdgcn_mfma_f32_16x16x32_bf16(         \
                    av[mi], bv[nj], acc[mi][nj], 0, 0, 0);                     \
    }

    ISSUE2(0, 0);
    int buf = 0;
    for (int k0 = 32; k0 < NI; k0 += 32) {
        ISSUE2(buf ^ 1, k0);
        __builtin_amdgcn_s_waitcnt(WAIT_VM3);
        __builtin_amdgcn_s_barrier();
        COMP2(buf);
        __builtin_amdgcn_s_barrier();
        buf ^= 1;
    }
    __builtin_amdgcn_s_waitcnt(WAIT_VM0);
    __builtin_amdgcn_s_barrier();
    COMP2(buf);

    #pragma unroll
    for (int mi = 0; mi < 4; mi++) {
        #pragma unroll
        for (int r = 0; r < 4; r++) {
            const int row = mt * 128 + rw * 64 + mi * 16 + quad * 4 + r;
            if (row < cnt) {
                const int p = base + row;
                const int t = pair_tok[p];
                const float wgt = pair_w[p];
                #pragma unroll
                for (int nj = 0; nj < 2; nj++) {
                    const int col = ct + cw * 32 + nj * 16 + lid;
                    atomicAdd(out + (size_t)t * NH + col, wgt * acc[mi][nj][r]);
                }
            }
        }
    }
#undef ISSUE2
#undef COMP2
}

// ---------------------------------------------------------------------------
extern "C" void kernel_launch(void* const* d_in, const int* in_sizes, int n_in,
                              void* d_out, int out_size, void* d_ws, size_t ws_size,
                              hipStream_t stream)
{
    const float* X      = (const float*)d_in[0];
    const float* logits = (const float*)d_in[1];
    const float* W13    = (const float*)d_in[2];
    const float* W2     = (const float*)d_in[3];
    float* out = (float*)d_out;

    char* ws = (char*)d_ws;
    int*   counts   = (int*)(ws + 0);
    int*   pair_tok = (int*)(ws + 256);
    float* pair_w   = (float*)(ws + 256 + 8192);
    u16*   Xb       = (u16*)(ws + 65536);                 // 2 MiB
    u16*   W13t     = (u16*)(ws + 4194304);               // 32 MiB [E][2I][H]
    u16*   W2t      = (u16*)(ws + 4194304 + 33554432);    // 16 MiB [E][H][I]
    u16*   act      = (u16*)(ws + 54525952);              // 4 MiB  [P][I]

    hipMemsetAsync(d_out, 0, (size_t)NTOK * NH * sizeof(float), stream);
    route_kernel<<<1, 256, 0, stream>>>(logits, counts, pair_tok, pair_w);
    cvt_x_kernel<<<512, 256, 0, stream>>>(X, Xb);
    cvt_tr_kernel<<<NE * 16 * 32, 256, 0, stream>>>(W13, W13t, NH, N13);
    cvt_tr_kernel<<<NE * 16 * 16, 256, 0, stream>>>(W2, W2t, NI, NH);

    const int grid1 = (NPAIR / 128 + NE - 1) * (NI / 64);   // 368 max
    const int grid2 = (NPAIR / 128 + NE - 1) * (NH / 64);   // 368 max
    gemm1_kernel<<<grid1, 256, 0, stream>>>(Xb, W13t, counts, pair_tok, act);
    gemm2_kernel<<<grid2, 256, 0, stream>>>(act, W2t, counts, pair_tok, pair_w, out);
}

// Round 6
// 190.162 us; speedup vs baseline: 1.0784x; 1.0527x over previous
//
#include <hip/hip_runtime.h>
#include <hip/hip_bf16.h>
#include <stdint.h>

#define NE    8
#define NTOK  1024
#define NH    1024
#define NI    1024
#define N13   2048
#define NPAIR 2048

typedef __attribute__((ext_vector_type(8))) short short8;
typedef __attribute__((ext_vector_type(4))) float f32x4;
typedef unsigned short u16;
typedef unsigned int   u32;

__device__ __forceinline__ u16 f2bf(float x) {
    union { float f; u32 u; } v; v.f = x;
    return (u16)((v.u + 0x7fffu + ((v.u >> 16) & 1u)) >> 16);
}

__device__ __forceinline__ void async_ld16(u16* lds, const u16* g) {
    __builtin_amdgcn_global_load_lds(
        (const __attribute__((address_space(1))) u32*)g,
        (__attribute__((address_space(3))) u32*)lds, 16, 0, 0);
}

// ---------------------------------------------------------------------------
// prep: block 0 = routing; blocks 1..512 = X fp32->bf16 convert
// ---------------------------------------------------------------------------
__global__ __launch_bounds__(256) void prep_kernel(
    const float* __restrict__ logits, const float* __restrict__ X,
    int* __restrict__ counts, int* __restrict__ pair_tok,
    float* __restrict__ pair_w, u16* __restrict__ Xb)
{
    const int tid = threadIdx.x;
    if (blockIdx.x > 0) {
        const int i = (blockIdx.x - 1) * 256 + tid;
        const float4* s = (const float4*)X;
        const float4 a = s[2 * i], b = s[2 * i + 1];
        uint4 o;
        o.x = f2bf(a.x) | ((u32)f2bf(a.y) << 16);
        o.y = f2bf(a.z) | ((u32)f2bf(a.w) << 16);
        o.z = f2bf(b.x) | ((u32)f2bf(b.y) << 16);
        o.w = f2bf(b.z) | ((u32)f2bf(b.w) << 16);
        *(uint4*)(Xb + (size_t)i * 8) = o;
        return;
    }

    __shared__ int s_cnt[NE];
    __shared__ int s_base[NE];
    if (tid < NE) s_cnt[tid] = 0;
    __syncthreads();

    int eA[4][2]; int slotA[4][2]; float wA[4][2];

    #pragma unroll
    for (int i = 0; i < 4; i++) {
        const int t = tid * 4 + i;
        float l[NE];
        #pragma unroll
        for (int e = 0; e < NE; e++) l[e] = logits[t * NE + e];
        int i0 = 0;
        #pragma unroll
        for (int e = 1; e < NE; e++) if (l[e] > l[i0]) i0 = e;
        int i1 = -1;
        #pragma unroll
        for (int e = 0; e < NE; e++) {
            if (e == i0) continue;
            if (i1 < 0 || l[e] > l[i1]) i1 = e;
        }
        const float e10 = __expf(l[i1] - l[i0]);
        const float inv = 1.0f / (1.0f + e10);
        eA[i][0] = i0; eA[i][1] = i1;
        wA[i][0] = inv; wA[i][1] = e10 * inv;
        slotA[i][0] = atomicAdd(&s_cnt[i0], 1);
        slotA[i][1] = atomicAdd(&s_cnt[i1], 1);
    }
    __syncthreads();
    if (tid == 0) {
        int acc = 0;
        #pragma unroll
        for (int e = 0; e < NE; e++) { s_base[e] = acc; acc += s_cnt[e]; }
    }
    __syncthreads();
    if (tid < NE) counts[tid] = s_cnt[tid];
    #pragma unroll
    for (int i = 0; i < 4; i++) {
        const int t = tid * 4 + i;
        #pragma unroll
        for (int k = 0; k < 2; k++) {
            const int p = s_base[eA[i][k]] + slotA[i][k];
            pair_tok[p] = t;
            pair_w[p]   = wA[i][k];
        }
    }
}

// ---------------------------------------------------------------------------
// Fused weight transpose+convert: W13 [E][H][2I] -> W13t [E][2I][H] and
// W2 [E][I][H] -> W2t [E][H][I], fp32->bf16, 64x64 LDS tiles.
// ---------------------------------------------------------------------------
__global__ __launch_bounds__(256) void cvt_w_kernel(
    const float* __restrict__ W13, u16* __restrict__ W13t,
    const float* __restrict__ W2, u16* __restrict__ W2t)
{
    __shared__ float Ts[64][65];
    const float* src; u16* dst; int K, N, bid;
    if (blockIdx.x < NE * 16 * 32) { src = W13; dst = W13t; K = NH; N = N13; bid = blockIdx.x; }
    else                           { src = W2;  dst = W2t;  K = NI; N = NH;  bid = blockIdx.x - NE * 16 * 32; }

    const int ktiles = K >> 6, ntiles = N >> 6;
    const int tpe = ktiles * ntiles;
    const int e = bid / tpe;
    const int rem = bid - e * tpe;
    const int kt = rem / ntiles, nt = rem - (rem / ntiles) * ntiles;
    const float* sb = src + ((size_t)e * K + (size_t)kt * 64) * N + nt * 64;
    const int tid = threadIdx.x;

    #pragma unroll
    for (int i = 0; i < 4; i++) {
        const int idx = tid + i * 256;
        const int r = idx >> 4, c = (idx & 15) << 2;
        const float4 v = *(const float4*)(sb + (size_t)r * N + c);
        Ts[r][c + 0] = v.x; Ts[r][c + 1] = v.y;
        Ts[r][c + 2] = v.z; Ts[r][c + 3] = v.w;
    }
    __syncthreads();
    u16* db = dst + ((size_t)e * N + (size_t)nt * 64) * K + kt * 64;
    #pragma unroll
    for (int i = 0; i < 2; i++) {
        const int u = tid + i * 256;
        const int n = u >> 3, k8 = (u & 7) << 3;
        uint4 o;
        o.x = f2bf(Ts[k8 + 0][n]) | ((u32)f2bf(Ts[k8 + 1][n]) << 16);
        o.y = f2bf(Ts[k8 + 2][n]) | ((u32)f2bf(Ts[k8 + 3][n]) << 16);
        o.z = f2bf(Ts[k8 + 4][n]) | ((u32)f2bf(Ts[k8 + 5][n]) << 16);
        o.w = f2bf(Ts[k8 + 6][n]) | ((u32)f2bf(Ts[k8 + 7][n]) << 16);
        *(uint4*)(db + (size_t)n * K + k8) = o;
    }
}

// ---------------------------------------------------------------------------
__device__ __forceinline__ bool find_tile(
    const int* __restrict__ counts, int tile, int bm, int ntn,
    int& e_o, int& mt_o, int& nt_o, int& cnt_o, int& base_o)
{
    int base = 0;
    #pragma unroll
    for (int e = 0; e < NE; e++) {
        const int cnt = counts[e];
        const int mtiles = (cnt + bm - 1) / bm;
        const int tiles = mtiles * ntn;
        if (tile < tiles) {
            e_o = e; mt_o = tile / ntn; nt_o = tile - (tile / ntn) * ntn;
            cnt_o = cnt; base_o = base; return true;
        }
        tile -= tiles; base += cnt;
    }
    return false;
}

// ---------------------------------------------------------------------------
// GEMM1: BM=128 pairs x 32 act cols (64 weight cols), BK=32, waves 2x2.
// Syncthreads-safe double buffer: barrier -> issue next chunk -> compute.
// XOR-swizzled LDS -> conflict-free b128 frag reads. grid ~736.
// ---------------------------------------------------------------------------
__global__ __launch_bounds__(256) void gemm1_kernel(
    const u16* __restrict__ Xb, const u16* __restrict__ W13t,
    const int* __restrict__ counts, const int* __restrict__ pair_tok,
    u16* __restrict__ act)
{
    int e, mt, nt, cnt, base;
    if (!find_tile(counts, blockIdx.x, 128, NI / 32, e, mt, nt, cnt, base)) return;

    __shared__ u16 As[2][128 * 32];   // [m][k], seg-swizzled
    __shared__ u16 Bs[2][64 * 32];    // rows 0..31 gate cols, 32..63 up cols

    const int tid = threadIdx.x;
    const int ct  = nt * 32;

    const int m0 = tid >> 2;
    const int sw16 = (((tid & 3) ^ (m0 & 3)) << 3);
    const int t0 = pair_tok[base + min(mt * 128 + m0, cnt - 1)];
    const int t1 = pair_tok[base + min(mt * 128 + 64 + m0, cnt - 1)];
    const u16* ga0 = Xb + (size_t)t0 * NH + sw16;
    const u16* ga1 = Xb + (size_t)t1 * NH + sw16;
    const int wcol = (m0 < 32) ? (ct + m0) : (NI + ct + m0 - 32);   // gate / up
    const u16* gb = W13t + ((size_t)e * N13 + wcol) * 1024 + sw16;

    const int lane = tid & 63, w = tid >> 6;
    const int quad = lane >> 4, lid = lane & 15;
    const int rw = w >> 1, cw = w & 1;
    const int fsw = (quad ^ (lid & 3)) << 3;
    int aoff[4];
    #pragma unroll
    for (int mi = 0; mi < 4; mi++)
        aoff[mi] = (rw * 64 + mi * 16 + lid) * 32 + fsw;
    const int bgoff = (cw * 16 + lid) * 32 + fsw;
    const int buoff = (32 + cw * 16 + lid) * 32 + fsw;

    f32x4 accg[4] = {};
    f32x4 accu[4] = {};

#define ISSUE1(b, k0)                                        \
    {                                                        \
        async_ld16(&As[b][tid * 8],         ga0 + (k0));     \
        async_ld16(&As[b][(tid + 256) * 8], ga1 + (k0));     \
        async_ld16(&Bs[b][tid * 8],         gb  + (k0));     \
    }
#define COMP1(b)                                                               \
    {                                                                          \
        short8 av[4];                                                          \
        _Pragma("unroll") for (int mi = 0; mi < 4; mi++)                       \
            av[mi] = *(const short8*)&As[b][aoff[mi]];                         \
        const short8 gv = *(const short8*)&Bs[b][bgoff];                       \
        const short8 uv = *(const short8*)&Bs[b][buoff];                       \
        _Pragma("unroll") for (int mi = 0; mi < 4; mi++) {                     \
            accg[mi] = __builtin_amdgcn_mfma_f32_16x16x32_bf16(                \
                av[mi], gv, accg[mi], 0, 0, 0);                                \
            accu[mi] = __builtin_amdgcn_mfma_f32_16x16x32_bf16(                \
                av[mi], uv, accu[mi], 0, 0, 0);                                \
        }                                                                      \
    }

    ISSUE1(0, 0);
    int buf = 0;
    for (int k0 = 32; k0 < NH; k0 += 32) {
        __syncthreads();          // drains buf's loads; prior reads of buf^1 done
        ISSUE1(buf ^ 1, k0);      // prefetch next chunk into other buffer
        COMP1(buf);
        buf ^= 1;
    }
    __syncthreads();
    COMP1(buf);

    const int col = ct + cw * 16 + lid;
    #pragma unroll
    for (int mi = 0; mi < 4; mi++) {
        #pragma unroll
        for (int r = 0; r < 4; r++) {
            const int row = mt * 128 + rw * 64 + mi * 16 + quad * 4 + r;
            if (row < cnt) {
                const float g = accg[mi][r], u = accu[mi][r];
                const float s = g / (1.0f + __expf(-g)) * u;
                act[(size_t)(base + row) * NI + col] = f2bf(s);
            }
        }
    }
#undef ISSUE1
#undef COMP1
}

// ---------------------------------------------------------------------------
// GEMM2: BM=64 pairs x BN=64 h cols, BK=32, waves 2x2. Same safe dbuf.
// Atomic scatter-combine into zeroed out (exactly 2 adds/element).
// ---------------------------------------------------------------------------
__global__ __launch_bounds__(256) void gemm2_kernel(
    const u16* __restrict__ act, const u16* __restrict__ W2t,
    const int* __restrict__ counts, const int* __restrict__ pair_tok,
    const float* __restrict__ pair_w, float* __restrict__ out)
{
    int e, mt, nt, cnt, base;
    if (!find_tile(counts, blockIdx.x, 64, NH / 64, e, mt, nt, cnt, base)) return;

    __shared__ u16 As[2][64 * 32];
    __shared__ u16 Bs[2][64 * 32];

    const int tid = threadIdx.x;
    const int ct  = nt * 64;

    const int m0 = tid >> 2;
    const int sw16 = (((tid & 3) ^ (m0 & 3)) << 3);
    const int p0 = base + min(mt * 64 + m0, cnt - 1);
    const u16* ga = act + (size_t)p0 * NI + sw16;
    const u16* gb = W2t + ((size_t)e * 1024 + ct + m0) * 1024 + sw16;

    const int lane = tid & 63, w = tid >> 6;
    const int quad = lane >> 4, lid = lane & 15;
    const int rw = w >> 1, cw = w & 1;
    const int fsw = (quad ^ (lid & 3)) << 3;
    int aoff[2], boff[2];
    #pragma unroll
    for (int mi = 0; mi < 2; mi++)
        aoff[mi] = (rw * 32 + mi * 16 + lid) * 32 + fsw;
    #pragma unroll
    for (int nj = 0; nj < 2; nj++)
        boff[nj] = (cw * 32 + nj * 16 + lid) * 32 + fsw;

    f32x4 acc[2][2] = {};

#define ISSUE2(b, k0)                                        \
    {                                                        \
        async_ld16(&As[b][tid * 8], ga + (k0));              \
        async_ld16(&Bs[b][tid * 8], gb + (k0));              \
    }
#define COMP2(b)                                                               \
    {                                                                          \
        short8 av[2], bv[2];                                                   \
        _Pragma("unroll") for (int mi = 0; mi < 2; mi++)                       \
            av[mi] = *(const short8*)&As[b][aoff[mi]];                         \
        _Pragma("unroll") for (int nj = 0; nj < 2; nj++)                       \
            bv[nj] = *(const short8*)&Bs[b][boff[nj]];                         \
        _Pragma("unroll") for (int mi = 0; mi < 2; mi++)                       \
            _Pragma("unroll") for (int nj = 0; nj < 2; nj++)                   \
                acc[mi][nj] = __builtin_amdgcn_mfma_f32_16x16x32_bf16(         \
                    av[mi], bv[nj], acc[mi][nj], 0, 0, 0);                     \
    }

    ISSUE2(0, 0);
    int buf = 0;
    for (int k0 = 32; k0 < NI; k0 += 32) {
        __syncthreads();
        ISSUE2(buf ^ 1, k0);
        COMP2(buf);
        buf ^= 1;
    }
    __syncthreads();
    COMP2(buf);

    #pragma unroll
    for (int mi = 0; mi < 2; mi++) {
        #pragma unroll
        for (int r = 0; r < 4; r++) {
            const int row = mt * 64 + rw * 32 + mi * 16 + quad * 4 + r;
            if (row < cnt) {
                const int p = base + row;
                const int t = pair_tok[p];
                const float wgt = pair_w[p];
                #pragma unroll
                for (int nj = 0; nj < 2; nj++) {
                    const int col = ct + cw * 32 + nj * 16 + lid;
                    atomicAdd(out + (size_t)t * NH + col, wgt * acc[mi][nj][r]);
                }
            }
        }
    }
#undef ISSUE2
#undef COMP2
}

// ---------------------------------------------------------------------------
extern "C" void kernel_launch(void* const* d_in, const int* in_sizes, int n_in,
                              void* d_out, int out_size, void* d_ws, size_t ws_size,
                              hipStream_t stream)
{
    const float* X      = (const float*)d_in[0];
    const float* logits = (const float*)d_in[1];
    const float* W13    = (const float*)d_in[2];
    const float* W2     = (const float*)d_in[3];
    float* out = (float*)d_out;

    char* ws = (char*)d_ws;
    int*   counts   = (int*)(ws + 0);
    int*   pair_tok = (int*)(ws + 256);
    float* pair_w   = (float*)(ws + 256 + 8192);
    u16*   Xb       = (u16*)(ws + 65536);                 // 2 MiB
    u16*   W13t     = (u16*)(ws + 4194304);               // 32 MiB [E][2I][H]
    u16*   W2t      = (u16*)(ws + 4194304 + 33554432);    // 16 MiB [E][H][I]
    u16*   act      = (u16*)(ws + 54525952);              // 4 MiB  [P][I]

    hipMemsetAsync(d_out, 0, (size_t)NTOK * NH * sizeof(float), stream);
    prep_kernel<<<513, 256, 0, stream>>>(logits, X, counts, pair_tok, pair_w, Xb);
    cvt_w_kernel<<<NE * 16 * 32 + NE * 16 * 16, 256, 0, stream>>>(W13, W13t, W2, W2t);

    const int grid1 = (NPAIR / 128 + NE - 1) * (NI / 32);   // 736 max
    const int grid2 = (NPAIR / 64 + NE - 1) * (NH / 64);    // 624 max
    gemm1_kernel<<<grid1, 256, 0, stream>>>(Xb, W13t, counts, pair_tok, act);
    gemm2_kernel<<<grid2, 256, 0, stream>>>(act, W2t, counts, pair_tok, pair_w, out);
}